// Round 6
// baseline (771.104 us; speedup 1.0000x reference)
//
#include <hip/hip_runtime.h>
#include <hip/hip_bf16.h>

typedef __bf16 bf16;
typedef __bf16 bf16x8 __attribute__((ext_vector_type(8)));
typedef __bf16 bf16x4 __attribute__((ext_vector_type(4)));
typedef float  f32x4  __attribute__((ext_vector_type(4)));

#define MFMA16(A,B,C) __builtin_amdgcn_mfma_f32_16x16x32_bf16((A),(B),(C),0,0,0)

constexpr int NI    = 64;     // instances
constexpr int NN    = 128;    // N (embedding rows / output cols)
constexpr int E     = 256;    // embed dim
constexpr int HID   = 1024;   // hidden
constexpr int BATCH = 2048;
constexpr int BM    = 256;    // batch rows per block (8 waves x 32 rows)
constexpr int BH    = 64;     // hidden chunk
// fallback-path LDS strides
constexpr int W1P   = E  + 8;
constexpr int W2P   = BH + 8;
constexpr int HP    = BH + 8;

__device__ __forceinline__ float fast_gelu(float x) {
    // tanh-form GELU: x * sigmoid(1.5957691*(x + 0.044715 x^3))
    float p = 1.5957691216f * __builtin_fmaf(0.044715f * x * x, x, x);
    return x * __builtin_amdgcn_rcpf(1.0f + __expf(-p));
}

// ---------------------------------------------------------------------------
// pack_w1 (verified r1): lin f32 [NI][E][HID] -> w1t bf16 "LDS image":
//   [i][h][p][j] = lin[ e=(p^(h&7))*8+j ][h]   (p: 16B chunk 0..31, j 0..7)
// 64-h slices are contiguous 32KB; XOR swizzle makes fused ds_read_b128
// conflict-free.
// ---------------------------------------------------------------------------
__global__ __launch_bounds__(256) void pack_w1(
    const float* __restrict__ in, bf16* __restrict__ out)
{
    __shared__ __align__(16) bf16 t[64][264];
    const int inst = blockIdx.y;
    const int h0   = blockIdx.x * 64;
    const int tid  = threadIdx.x;
    {
        const int hq = tid & 15;
        const int e0 = tid >> 4;
        const float* ip = in + (size_t)inst * E * HID + h0 + hq * 4;
        #pragma unroll
        for (int it = 0; it < 16; ++it) {
            int e = it * 16 + e0;
            f32x4 v = *(const f32x4*)(ip + (size_t)e * HID);
            #pragma unroll
            for (int k = 0; k < 4; ++k) t[hq * 4 + k][e] = (bf16)v[k];
        }
    }
    __syncthreads();
    bf16* op = out + ((size_t)inst * HID + h0) * E;
    #pragma unroll
    for (int it = 0; it < 8; ++it) {
        int o  = it * 256 + tid;
        int hl = o >> 5, p = o & 31;
        int tt = p ^ (hl & 7);
        bf16x8 v = *(const bf16x8*)&t[hl][tt * 8];
        *(bf16x8*)(op + (size_t)o * 8) = v;
    }
}

// ---------------------------------------------------------------------------
// pack_w2 (verified r1): une f32 [NI][HID][NN] -> w2t bf16 [i][n][c16][p8][j8]:
//   t = p^(n&7), k2=t>>2, q=t&3:
//   j<4:  h = c*64 + k2*32 + q*4 + j ;  j>=4: h = c*64 + k2*32 + 16 + q*4 + (j-4)
// Bakes GEMM2's K-permutation (so in-register gelu'd H is a legal A-fragment)
// AND the bank swizzle into the global layout.
// ---------------------------------------------------------------------------
__global__ __launch_bounds__(256) void pack_w2(
    const float* __restrict__ in, bf16* __restrict__ out)
{
    __shared__ __align__(16) bf16 t[128][68];
    const int inst = blockIdx.y;
    const int c    = blockIdx.x;                // 64-h chunk
    const int tid  = threadIdx.x;
    {
        const int nq = tid & 31;
        const int h0 = tid >> 5;
        const float* ip = in + ((size_t)inst * HID + c * 64) * NN + nq * 4;
        #pragma unroll
        for (int it = 0; it < 8; ++it) {
            int h = it * 8 + h0;
            f32x4 v = *(const f32x4*)(ip + (size_t)h * NN);
            #pragma unroll
            for (int k = 0; k < 4; ++k) t[nq * 4 + k][h] = (bf16)v[k];
        }
    }
    __syncthreads();
    bf16* ob = out + (size_t)inst * NN * HID + (size_t)c * 64;
    #pragma unroll
    for (int it = 0; it < 4; ++it) {
        int o = it * 256 + tid;
        int n = o >> 3, p = o & 7;
        int tt = p ^ (n & 7);
        int k2 = tt >> 2, qq = tt & 3;
        const bf16* r0 = &t[n][k2 * 32 + qq * 4];
        bf16x4 lo = *(const bf16x4*)r0;
        bf16x4 hi = *(const bf16x4*)(r0 + 16);
        bf16x8 v;
        v[0] = lo[0]; v[1] = lo[1]; v[2] = lo[2]; v[3] = lo[3];
        v[4] = hi[0]; v[5] = hi[1]; v[6] = hi[2]; v[7] = hi[3];
        *(bf16x8*)(ob + (size_t)n * 1024 + p * 8) = v;
    }
}

// ---------------------------------------------------------------------------
// Fused MLP v5: identical inner loop to v4 (in-register GEMM2, T14 reg-staged
// prefetch, swizzled packed weights), but 8 waves / BM=256 / 512 threads:
// grid 512 = one residency round at 2 blocks/CU = 16 waves/CU (4/SIMD) --
// double the TLP of v4 with the same 48KB LDS and same per-wave registers.
// ---------------------------------------------------------------------------
__global__ __launch_bounds__(512, 4) void mlp3_fused_v5(
    const int*   __restrict__ a,
    const float* __restrict__ embL,
    const float* __restrict__ embR,
    const bf16*  __restrict__ W1,   // packed [NI][HID][32 chunk][8]
    const bf16*  __restrict__ W2,   // packed [NI][NN][16 c][8 chunk][8]
    float* __restrict__ out)
{
    __shared__ __align__(16) bf16 sW1[BH * E];   // 32 KB
    __shared__ __align__(16) bf16 sW2[NN * BH];  // 16 KB

    // XCD swizzle: 8 consecutive blocks per XCD share an instance.
    const int blk   = blockIdx.x;            // 0..511
    const int xcd   = blk & 7;
    const int j     = blk >> 3;              // 0..63
    const int inst  = xcd + 8 * (j >> 3);
    const int btile = j & 7;                 // 0..7 (256-row tiles)

    const int tid  = threadIdx.x;
    const int wave = tid >> 6;               // 0..7
    const int lane = tid & 63;
    const int m  = lane & 15;
    const int q  = lane >> 4;
    const int xm = m & 7;

    const char* w1g = (const char*)W1 + (size_t)inst * (HID * E * 2);
    const char* w2g = (const char*)W2 + (size_t)inst * (NN * HID * 2);
    char* s1 = (char*)sW1;
    char* s2 = (char*)sW2;

    // staging registers: 4x W1 + 2x W2 fragments of 16B per wave
    bf16x8 rg[6];

    // ---- prologue: issue chunk-0 loads (land while aF is built) ----
    {
        #pragma unroll
        for (int it = 0; it < 4; ++it) {
            const int b = it * 8 + wave;
            rg[it] = *(const bf16x8*)(w1g + b * 1024 + lane * 16);
        }
        #pragma unroll
        for (int it = 0; it < 2; ++it) {
            const int b = it * 8 + wave;
            const int n = b * 8 + (lane >> 3);
            rg[4 + it] = *(const bf16x8*)(w2g + (size_t)n * 2048 + (lane & 7) * 16);
        }
    }

    // ---- A fragments: this wave's 32 batch rows x 256 e, bf16 in registers ----
    bf16x8 aF[2][8];
    #pragma unroll
    for (int rt = 0; rt < 2; ++rt) {
        const int r  = btile * BM + wave * 32 + rt * 16 + m;
        const int i1 = a[2 * r + 0];
        const int i2 = a[2 * r + 1];
        const float* pl = embL + ((size_t)inst * NN + i1) * E;
        const float* pr = embR + ((size_t)inst * NN + i2) * E;
        #pragma unroll
        for (int ks = 0; ks < 8; ++ks) {
            const int e0 = ks * 32 + q * 8;
            f32x4 l0 = *(const f32x4*)(pl + e0);
            f32x4 l1 = *(const f32x4*)(pl + e0 + 4);
            f32x4 r0 = *(const f32x4*)(pr + e0);
            f32x4 r1 = *(const f32x4*)(pr + e0 + 4);
            bf16x8 s;
            #pragma unroll
            for (int k = 0; k < 4; ++k) {
                s[k]     = (bf16)(l0[k] + r0[k]);
                s[k + 4] = (bf16)(l1[k] + r1[k]);
            }
            aF[rt][ks] = s;
        }
    }

    f32x4 O[2][8];
    #pragma unroll
    for (int rt = 0; rt < 2; ++rt)
        #pragma unroll
        for (int ct = 0; ct < 8; ++ct)
            O[rt][ct] = (f32x4){0.f, 0.f, 0.f, 0.f};

    #pragma unroll 1
    for (int c = 0; c < HID / BH; ++c) {
        __syncthreads();   // B1: prev chunk's LDS reads done before restage
        // ---- write staged regs (chunk c) to LDS ----
        #pragma unroll
        for (int it = 0; it < 4; ++it) {
            const int b = it * 8 + wave;
            *(bf16x8*)(s1 + b * 1024 + lane * 16) = rg[it];
        }
        #pragma unroll
        for (int it = 0; it < 2; ++it) {
            const int b = it * 8 + wave;
            *(bf16x8*)(s2 + b * 1024 + lane * 16) = rg[4 + it];
        }
        __syncthreads();   // B2: chunk c visible to all waves

        // ---- T14: issue chunk c+1 loads now; they land under the MFMAs ----
        if (c + 1 < HID / BH) {
            const char* g1 = w1g + (size_t)(c + 1) * (BH * E * 2);
            #pragma unroll
            for (int it = 0; it < 4; ++it) {
                const int b = it * 8 + wave;
                rg[it] = *(const bf16x8*)(g1 + b * 1024 + lane * 16);
            }
            const char* g2 = w2g + (size_t)(c + 1) * 128;
            #pragma unroll
            for (int it = 0; it < 2; ++it) {
                const int b = it * 8 + wave;
                const int n = b * 8 + (lane >> 3);
                rg[4 + it] = *(const bf16x8*)(g2 + (size_t)n * 2048 + (lane & 7) * 16);
            }
        }

        // ---- compute chunk c (verified r1/v4 math) ----
        #pragma unroll
        for (int k2 = 0; k2 < 2; ++k2) {
            bf16x8 pa[2];
            #pragma unroll
            for (int cth = 0; cth < 2; ++cth) {
                const int ct = k2 * 2 + cth;
                // GEMM1 (swapped): S^T tile = mfma(W1frag, aF)
                f32x4 S0 = (f32x4){0.f, 0.f, 0.f, 0.f};
                f32x4 S1 = (f32x4){0.f, 0.f, 0.f, 0.f};
                #pragma unroll
                for (int ks = 0; ks < 8; ++ks) {
                    const int sw = ((ks * 4 + q) ^ xm) * 16;
                    bf16x8 w1f = *(const bf16x8*)(s1 + (ct * 16 + m) * 512 + sw);
                    S0 = MFMA16(w1f, aF[0][ks], S0);
                    S1 = MFMA16(w1f, aF[1][ks], S1);
                }
                // gelu + pack: lane holds 4 h-consecutive values per tile
                #pragma unroll
                for (int rr = 0; rr < 4; ++rr) {
                    pa[0][cth * 4 + rr] = (bf16)fast_gelu(S0[rr]);
                    pa[1][cth * 4 + rr] = (bf16)fast_gelu(S1[rr]);
                }
            }
            // GEMM2: A = pa (registers), B = packed W2 (K-perm baked in)
            #pragma unroll
            for (int ct2 = 0; ct2 < 8; ++ct2) {
                const int sw = ((k2 * 4 + q) ^ xm) * 16;
                bf16x8 w2f = *(const bf16x8*)(s2 + (ct2 * 16 + m) * 128 + sw);
                O[0][ct2] = MFMA16(pa[0], w2f, O[0][ct2]);
                O[1][ct2] = MFMA16(pa[1], w2f, O[1][ct2]);
            }
        }
    }

    // ---- epilogue: out[b, inst, n] fp32 ----
    #pragma unroll
    for (int rt = 0; rt < 2; ++rt)
        #pragma unroll
        for (int ct = 0; ct < 8; ++ct)
            #pragma unroll
            for (int rr = 0; rr < 4; ++rr) {
                const int b = btile * BM + wave * 32 + rt * 16 + q * 4 + rr;
                const int n = ct * 16 + m;
                out[((size_t)b * NI + inst) * NN + n] = O[rt][ct][rr];
            }
}

// ---------------------------------------------------------------------------
// Fallback (no workspace): v1 kernel with f32 weights, in-kernel transpose.
// ---------------------------------------------------------------------------
__global__ __launch_bounds__(256, 2) void mlp3_fallback(
    const int*   __restrict__ a,
    const float* __restrict__ embL,
    const float* __restrict__ embR,
    const float* __restrict__ W1,   // [NI][E][HID] f32
    const float* __restrict__ W2,   // [NI][HID][NN] f32
    float* __restrict__ out)
{
    __shared__ __align__(16) bf16 sW1[BH][W1P];
    __shared__ __align__(16) bf16 sW2[NN][W2P];
    __shared__ __align__(16) bf16 sH [128][HP];

    const int blk   = blockIdx.x;
    const int xcd   = blk & 7;
    const int j     = blk >> 3;
    const int inst  = xcd + 8 * (j >> 4);
    const int btile = j & 15;

    const int tid  = threadIdx.x;
    const int wave = tid >> 6;
    const int lane = tid & 63;
    const int m = lane & 15;
    const int q = lane >> 4;

    bf16x8 aF[2][8];
    #pragma unroll
    for (int rt = 0; rt < 2; ++rt) {
        const int r  = btile * 128 + wave * 32 + rt * 16 + m;
        const int i1 = a[2 * r + 0];
        const int i2 = a[2 * r + 1];
        const float* pl = embL + ((size_t)inst * NN + i1) * E;
        const float* pr = embR + ((size_t)inst * NN + i2) * E;
        #pragma unroll
        for (int ks = 0; ks < 8; ++ks) {
            const int e0 = ks * 32 + q * 8;
            f32x4 l0 = *(const f32x4*)(pl + e0);
            f32x4 l1 = *(const f32x4*)(pl + e0 + 4);
            f32x4 r0 = *(const f32x4*)(pr + e0);
            f32x4 r1 = *(const f32x4*)(pr + e0 + 4);
            bf16x8 s;
            #pragma unroll
            for (int k = 0; k < 4; ++k) {
                s[k]     = (bf16)(l0[k] + r0[k]);
                s[k + 4] = (bf16)(l1[k] + r1[k]);
            }
            aF[rt][ks] = s;
        }
    }

    f32x4 O[2][8];
    #pragma unroll
    for (int rt = 0; rt < 2; ++rt)
        #pragma unroll
        for (int ct = 0; ct < 8; ++ct)
            O[rt][ct] = (f32x4){0.f, 0.f, 0.f, 0.f};

    #pragma unroll 1
    for (int c = 0; c < HID / BH; ++c) {
        __syncthreads();
        #pragma unroll
        for (int it = 0; it < 8; ++it) {
            const int idx = it * 256 + tid;
            const int e = idx >> 3, h8 = idx & 7;
            f32x4 v0 = *(const f32x4*)(W1 + ((size_t)inst * E + e) * HID + c * BH + h8 * 8);
            f32x4 v1 = *(const f32x4*)(W1 + ((size_t)inst * E + e) * HID + c * BH + h8 * 8 + 4);
            #pragma unroll
            for (int k = 0; k < 4; ++k) {
                sW1[h8 * 8 + k][e]     = (bf16)v0[k];
                sW1[h8 * 8 + k + 4][e] = (bf16)v1[k];
            }
        }
        #pragma unroll
        for (int it = 0; it < 4; ++it) {
            const int idx = it * 256 + tid;
            const int h = idx >> 4, n8 = idx & 15;
            f32x4 v0 = *(const f32x4*)(W2 + ((size_t)inst * HID + c * BH + h) * NN + n8 * 8);
            f32x4 v1 = *(const f32x4*)(W2 + ((size_t)inst * HID + c * BH + h) * NN + n8 * 8 + 4);
            #pragma unroll
            for (int k = 0; k < 4; ++k) {
                sW2[n8 * 8 + k][h]     = (bf16)v0[k];
                sW2[n8 * 8 + k + 4][h] = (bf16)v1[k];
            }
        }
        __syncthreads();

        f32x4 S[2][4];
        #pragma unroll
        for (int rt = 0; rt < 2; ++rt)
            #pragma unroll
            for (int ct = 0; ct < 4; ++ct) S[rt][ct] = (f32x4){0.f, 0.f, 0.f, 0.f};
        #pragma unroll
        for (int ks = 0; ks < 8; ++ks) {
            #pragma unroll
            for (int ct = 0; ct < 4; ++ct) {
                bf16x8 b = *(const bf16x8*)&sW1[ct * 16 + m][ks * 32 + q * 8];
                S[0][ct] = MFMA16(aF[0][ks], b, S[0][ct]);
                S[1][ct] = MFMA16(aF[1][ks], b, S[1][ct]);
            }
        }

        #pragma unroll
        for (int rt = 0; rt < 2; ++rt)
            #pragma unroll
            for (int ct = 0; ct < 4; ++ct)
                #pragma unroll
                for (int rr = 0; rr < 4; ++rr)
                    sH[wave * 32 + rt * 16 + q * 4 + rr][ct * 16 + m] =
                        (bf16)fast_gelu(S[rt][ct][rr]);
        asm volatile("s_waitcnt lgkmcnt(0)" ::: "memory");

        #pragma unroll
        for (int k2 = 0; k2 < 2; ++k2) {
            bf16x8 h0 = *(const bf16x8*)&sH[wave * 32 +  0 + m][k2 * 32 + q * 8];
            bf16x8 h1 = *(const bf16x8*)&sH[wave * 32 + 16 + m][k2 * 32 + q * 8];
            #pragma unroll
            for (int ct = 0; ct < 8; ++ct) {
                bf16x8 b = *(const bf16x8*)&sW2[ct * 16 + m][k2 * 32 + q * 8];
                O[0][ct] = MFMA16(h0, b, O[0][ct]);
                O[1][ct] = MFMA16(h1, b, O[1][ct]);
            }
        }
    }

    #pragma unroll
    for (int rt = 0; rt < 2; ++rt)
        #pragma unroll
        for (int ct = 0; ct < 8; ++ct)
            #pragma unroll
            for (int rr = 0; rr < 4; ++rr) {
                const int b = btile * 128 + wave * 32 + rt * 16 + q * 4 + rr;
                const int n = ct * 16 + m;
                out[((size_t)b * NI + inst) * NN + n] = O[rt][ct][rr];
            }
}

extern "C" void kernel_launch(void* const* d_in, const int* in_sizes, int n_in,
                              void* d_out, int out_size, void* d_ws, size_t ws_size,
                              hipStream_t stream)
{
    const int*   a    = (const int*)d_in[0];
    const float* embL = (const float*)d_in[1];
    const float* embR = (const float*)d_in[2];
    const float* lin  = (const float*)d_in[3];   // [NI][E][HID] f32
    const float* une  = (const float*)d_in[4];   // [NI][HID][NN] f32
    float* out = (float*)d_out;

    const size_t w1t_elems = (size_t)NI * HID * E;   // 16.78M bf16
    const size_t w2t_elems = (size_t)NI * NN * HID;  //  8.39M bf16
    const size_t need = (w1t_elems + w2t_elems) * sizeof(bf16);  // ~50 MB

    if (ws_size >= need) {
        bf16* w1t = (bf16*)d_ws;
        bf16* w2t = w1t + w1t_elems;
        pack_w1<<<dim3(HID / 64, NI), 256, 0, stream>>>(lin, w1t);
        pack_w2<<<dim3(HID / 64, NI), 256, 0, stream>>>(une, w2t);
        mlp3_fused_v5<<<(BATCH / BM) * NI, 512, 0, stream>>>(
            a, embL, embR, w1t, w2t, out);
    } else {
        mlp3_fallback<<<(BATCH / 128) * NI, 256, 0, stream>>>(
            a, embL, embR, lin, une, out);
    }
}